// Round 12
// baseline (200.657 us; speedup 1.0000x reference)
//
#include <hip/hip_runtime.h>

#define SEQ   2048
#define NH    16
#define HD    64
#define EMB   1024
#define NB    4
#define MTOT  (NB*SEQ)   // 8192
#define NT    (SEQ/64)   // 32 kv/q tiles per sequence

typedef _Float16 f16;
typedef _Float16 f16x4 __attribute__((ext_vector_type(4)));
typedef _Float16 f16x8 __attribute__((ext_vector_type(8)));
typedef float    f32x4 __attribute__((ext_vector_type(4)));

#define MFMA_F16(a,b,c) __builtin_amdgcn_mfma_f32_16x16x32_f16(a,b,c,0,0,0)

// Q pre-scale folded into the Q-projection epilogue: 1/sqrt(64) * log2(e)
#define QSCALE 0.18033688011112043f

__device__ __forceinline__ float fast_exp2(float x) {
#if __has_builtin(__builtin_amdgcn_exp2f)
  return __builtin_amdgcn_exp2f(x);
#else
  return exp2f(x);
#endif
}

// global -> LDS direct (16B per lane). LDS dst is wave-uniform base + lane*16.
__device__ __forceinline__ void gload16(const f16* g, f16* l) {
  __builtin_amdgcn_global_load_lds(
      (const __attribute__((address_space(1))) void*)g,
      (__attribute__((address_space(3))) void*)l, 16, 0, 0);
}

// ---------------------------------------------------------------------------
// Prep: cast x (fp32) -> fp16
// ---------------------------------------------------------------------------
__global__ __launch_bounds__(256) void cast_x_kernel(
    const float* __restrict__ x, f16* __restrict__ xh) {
  size_t i = ((size_t)blockIdx.x * 256 + threadIdx.x) * 8;
  float4 a = *(const float4*)(x + i);
  float4 b = *(const float4*)(x + i + 4);
  f16x8 o;
  o[0]=(f16)a.x; o[1]=(f16)a.y; o[2]=(f16)a.z; o[3]=(f16)a.w;
  o[4]=(f16)b.x; o[5]=(f16)b.y; o[6]=(f16)b.z; o[7]=(f16)b.w;
  *(f16x8*)(xh + i) = o;
}

// ---------------------------------------------------------------------------
// Prep: Wt[n][k] = (f16) W[k][n]   (64x64 tiles through LDS)
// ---------------------------------------------------------------------------
__global__ __launch_bounds__(256) void wtrans_kernel(
    const float* __restrict__ W0, const float* __restrict__ W1,
    const float* __restrict__ W2, const float* __restrict__ W3,
    f16* __restrict__ O0, f16* __restrict__ O1,
    f16* __restrict__ O2, f16* __restrict__ O3) {
  const int z = blockIdx.z;
  const float* W = (z==0)?W0:(z==1)?W1:(z==2)?W2:W3;
  f16* O        = (z==0)?O0:(z==1)?O1:(z==2)?O2:O3;
  __shared__ float Tl[64][68];
  const int t = threadIdx.x;
  const int k0 = blockIdx.x * 64, n0 = blockIdx.y * 64;
  {
    const int r = t >> 2, c0 = (t & 3) * 16;
    const float* src = W + (size_t)(k0 + r) * EMB + n0 + c0;
    #pragma unroll
    for (int j = 0; j < 4; ++j) {
      float4 v = *(const float4*)(src + 4 * j);
      Tl[c0+4*j+0][r]=v.x; Tl[c0+4*j+1][r]=v.y;
      Tl[c0+4*j+2][r]=v.z; Tl[c0+4*j+3][r]=v.w;
    }
  }
  __syncthreads();
  {
    const int n = t >> 2, c0 = (t & 3) * 16;
    f16* dst = O + (size_t)(n0 + n) * EMB + k0 + c0;
    #pragma unroll
    for (int j = 0; j < 2; ++j) {
      f16x8 o;
      #pragma unroll
      for (int u = 0; u < 8; ++u) o[u] = (f16)Tl[n][c0 + 8*j + u];
      *(f16x8*)(dst + 8 * j) = o;
    }
  }
}

// ---------------------------------------------------------------------------
// fp16 NT GEMM core: C[m][n] = (sum_k A[m][k] * Bt[n][k] + bias[n]) * scale
// 128x128 tile, BK=64, 4 waves of 64x64, global_load_lds + XOR-swizzled LDS.
// MODE 0: out f16 [B,H,T,D] (q/k)   MODE 1: out f16 [B,H,D,T] (v transposed)
// MODE 2: out f32 row-major [M,N]
// ---------------------------------------------------------------------------
template<int MODE>
__device__ __forceinline__ void gemm_core(
    const f16* __restrict__ A, const f16* __restrict__ Bt,
    const float* __restrict__ bias, void* __restrict__ out,
    int m0, int n0, float scale) {
  __shared__ f16 As[128 * 64];
  __shared__ f16 Bs[128 * 64];
  const int tid  = threadIdx.x;
  const int lane = tid & 63, w = tid >> 6;
  const int g = lane >> 4, lx = lane & 15;
  const int wr = w >> 1, wc = w & 1;
  const int sr = lane >> 3, sc = lane & 7;

  f32x4 acc[4][4];
  const f32x4 z4 = {0.f, 0.f, 0.f, 0.f};
  #pragma unroll
  for (int i = 0; i < 4; ++i)
    #pragma unroll
    for (int j = 0; j < 4; ++j) acc[i][j] = z4;

  for (int k0 = 0; k0 < EMB; k0 += 64) {
    __syncthreads();
    #pragma unroll
    for (int ci = 0; ci < 4; ++ci) {
      const int i = 4 * w + ci;
      const int r = i * 8 + sr;
      const int c = sc ^ (r & 7);
      gload16(A  + (size_t)(m0 + r) * EMB + k0 + c * 8, &As[i * 512]);
      gload16(Bt + (size_t)(n0 + r) * EMB + k0 + c * 8, &Bs[i * 512]);
    }
    __syncthreads();

    #pragma unroll
    for (int h = 0; h < 2; ++h) {
      f16x8 af[4], bf[4];
      #pragma unroll
      for (int mf = 0; mf < 4; ++mf) {
        const int row = wr * 64 + mf * 16 + lx;
        const int off = (row * 128 + h * 64 + g * 16) ^ ((row & 7) << 4);
        af[mf] = *(const f16x8*)((const char*)As + off);
      }
      #pragma unroll
      for (int nf = 0; nf < 4; ++nf) {
        const int row = wc * 64 + nf * 16 + lx;
        const int off = (row * 128 + h * 64 + g * 16) ^ ((row & 7) << 4);
        bf[nf] = *(const f16x8*)((const char*)Bs + off);
      }
      #pragma unroll
      for (int mf = 0; mf < 4; ++mf)
        #pragma unroll
        for (int nf = 0; nf < 4; ++nf)
          acc[mf][nf] = MFMA_F16(af[mf], bf[nf], acc[mf][nf]);
    }
  }

  // epilogue: C/D layout col = lane&15, row = (lane>>4)*4 + reg
  #pragma unroll
  for (int mf = 0; mf < 4; ++mf) {
    #pragma unroll
    for (int nf = 0; nf < 4; ++nf) {
      const int n  = n0 + wc * 64 + nf * 16 + lx;
      const int mb = m0 + wr * 64 + mf * 16 + g * 4;
      const float bv = bias[n];
      if (MODE == 2) {
        float* op = (float*)out;
        #pragma unroll
        for (int r = 0; r < 4; ++r)
          op[(size_t)(mb + r) * EMB + n] = acc[mf][nf][r] + bv;
      } else {
        const int b = mb >> 11, tt = mb & (SEQ - 1);
        const int hh = n >> 6, d = n & (HD - 1);
        f16* op = (f16*)out;
        if (MODE == 0) {
          #pragma unroll
          for (int r = 0; r < 4; ++r)
            op[((size_t)(b * NH + hh) * SEQ + tt + r) * HD + d] =
                (f16)((acc[mf][nf][r] + bv) * scale);
        } else {
          f16x4 o;
          #pragma unroll
          for (int r = 0; r < 4; ++r) o[r] = (f16)(acc[mf][nf][r] + bv);
          *(f16x4*)(op + ((size_t)(b * NH + hh) * HD + d) * SEQ + tt) = o;
        }
      }
    }
  }
}

// merged Q/K/V projections: one dispatch, grid.z = 3 -> 1536 blocks in flight
__global__ __launch_bounds__(256) void qkv_gemm_kernel(
    const f16* __restrict__ xh, const f16* __restrict__ wqt,
    const f16* __restrict__ wkt, const f16* __restrict__ wvt,
    const float* __restrict__ bq, const float* __restrict__ bk,
    const float* __restrict__ bv,
    f16* __restrict__ qh, f16* __restrict__ kh, f16* __restrict__ vth) {
  const int z = blockIdx.z;
  const int m0 = blockIdx.x * 128, n0 = blockIdx.y * 128;
  if (z == 0)      gemm_core<0>(xh, wqt, bq, qh, m0, n0, QSCALE);
  else if (z == 1) gemm_core<0>(xh, wkt, bk, kh, m0, n0, 1.0f);
  else             gemm_core<1>(xh, wvt, bv, vth, m0, n0, 1.0f);
}

__global__ __launch_bounds__(256) void proj_gemm_kernel(
    const f16* __restrict__ ath, const f16* __restrict__ wot,
    const float* __restrict__ bo, float* __restrict__ out) {
  gemm_core<2>(ath, wot, bo, out, blockIdx.x * 128, blockIdx.y * 128, 1.0f);
}

// ---------------------------------------------------------------------------
// Causal flash attention, fp16 MFMA, triangle-paired, XCD-pinned, kv-split=2,
// PER-PART P BUFFERS (removes the SM0-waits-for-PV1 LDS hazard; lets PV MFMAs
// overlap the other part's softmax VALU in the scheduler).
// q,k: [B,H,T,D] (q pre-scaled by 0.125*log2e); v: [B,H,D,T].
// 1D grid of 2048; decode xcd=bid&7 -> all 32 blocks of one (b,h) on ONE XCD.
// Each block: kv tiles of one parity for pair (qlo=p, qhi=31-p); emits
// unnormalized partials (m,l,O); combine_kernel merges the two splits.
// ---------------------------------------------------------------------------
__global__ __launch_bounds__(256, 4) void attn_kernel(
    const f16* __restrict__ Qh, const f16* __restrict__ Kh,
    const f16* __restrict__ Vth, f16* __restrict__ Opart,
    float* __restrict__ mPart, float* __restrict__ lPart) {
  __shared__ f16 Ks[64 * 64];
  __shared__ f16 Vs[64 * 64];
  __shared__ f16 Ps[4][2][16 * 64];   // [wave][part]
  const int tid  = threadIdx.x;
  const int lane = tid & 63, w = tid >> 6;
  const int g = lane >> 4, lx = lane & 15;
  const int sr = lane >> 3, sc = lane & 7;
  const int bid = blockIdx.x;
  const int xcd   = bid & 7;
  const int idx   = bid >> 3;          // 0..255
  const int split = idx & 1;           // kv tile parity
  const int p     = (idx >> 1) & 15;   // pair index 0..15
  const int bh    = xcd + 8 * (idx >> 5);
  const int qlo = p, qhi = NT - 1 - p;
  const int nkt = qhi + 1;
  const f16* qp = Qh  + (size_t)bh * SEQ * HD;
  const f16* kp = Kh  + (size_t)bh * SEQ * HD;
  const f16* vp = Vth + (size_t)bh * HD * SEQ;
  const int row0[2] = {qlo * 64 + w * 16, qhi * 64 + w * 16};

  // Q fragments for both parts (B-operand); scale already folded in.
  f16x8 qf[2][2];
  #pragma unroll
  for (int part = 0; part < 2; ++part) {
    const int qrow = row0[part] + lx;
    #pragma unroll
    for (int h = 0; h < 2; ++h)
      qf[part][h] = *(const f16x8*)(qp + (size_t)qrow * HD + h * 32 + g * 8);
  }

  const f32x4 z4 = {0.f, 0.f, 0.f, 0.f};
  f32x4 oa[2][4];
  float m_i[2] = {-1e30f, -1e30f}, l_i[2] = {0.f, 0.f};
  #pragma unroll
  for (int part = 0; part < 2; ++part)
    #pragma unroll
    for (int df = 0; df < 4; ++df) oa[part][df] = z4;

  for (int kt = split; kt < nkt; kt += 2) {
    __syncthreads();   // prior iter's LDS reads done before overwrite
    #pragma unroll
    for (int ci = 0; ci < 2; ++ci) {
      const int i = 2 * w + ci;
      const int r = i * 8 + sr;
      const int c = sc ^ (r & 7);
      gload16(kp + (size_t)(kt * 64 + r) * HD + c * 8, &Ks[i * 512]);
      gload16(vp + (size_t)r * SEQ + kt * 64 + c * 8,  &Vs[i * 512]);
    }
    __syncthreads();

    const bool dual = (kt <= qlo);

    // softmax + P-store for one part (R9/R11 body, unchanged semantics)
    auto sm_store = [&](int part, f32x4* sa, bool diag) {
      const int qrow = row0[part] + lx;
      float rmax = -1e30f;
      #pragma unroll
      for (int sf = 0; sf < 4; ++sf)
        #pragma unroll
        for (int r = 0; r < 4; ++r) {
          float vsc = sa[sf][r];
          if (diag) {
            const int kv = kt * 64 + sf * 16 + g * 4 + r;
            if (kv > qrow) vsc = -1e30f;
          }
          sa[sf][r] = vsc;
          rmax = fmaxf(rmax, vsc);
        }
      rmax = fmaxf(rmax, __shfl_xor(rmax, 16));
      rmax = fmaxf(rmax, __shfl_xor(rmax, 32));
      const float mnew = fmaxf(m_i[part], rmax);
      const float corr = fast_exp2(m_i[part] - mnew);
      m_i[part] = mnew;
      float rsum = 0.f;
      #pragma unroll
      for (int sf = 0; sf < 4; ++sf)
        #pragma unroll
        for (int r = 0; r < 4; ++r) {
          const float pv = fast_exp2(sa[sf][r] - mnew);
          sa[sf][r] = pv;
          rsum += pv;
        }
      rsum += __shfl_xor(rsum, 16);
      rsum += __shfl_xor(rsum, 32);
      l_i[part] = l_i[part] * corr + rsum;

      // P -> per-wave, PER-PART LDS transposed to [q=lx][kv] (swizzled)
      #pragma unroll
      for (int sf = 0; sf < 4; ++sf) {
        f16x4 p4;
        #pragma unroll
        for (int r = 0; r < 4; ++r) p4[r] = (f16)sa[sf][r];
        const int off = (lx * 128 + sf * 32 + g * 8) ^ ((lx & 7) << 4);
        *(f16x4*)((char*)Ps[w][part] + off) = p4;
      }

      // rescale O (row m = g*4+r; its corr lives in lane g*4+r)
      #pragma unroll
      for (int r = 0; r < 4; ++r) {
        const float cr = __shfl(corr, g * 4 + r, 64);
        #pragma unroll
        for (int df = 0; df < 4; ++df) oa[part][df][r] *= cr;
      }
    };

    auto pv_acc = [&](int part) {
      __builtin_amdgcn_s_setprio(1);
      #pragma unroll
      for (int hk = 0; hk < 2; ++hk) {
        const int offp = (lx * 128 + hk * 64 + g * 16) ^ ((lx & 7) << 4);
        f16x8 pf = *(const f16x8*)((const char*)Ps[w][part] + offp);
        #pragma unroll
        for (int df = 0; df < 4; ++df) {
          const int row = df * 16 + lx;
          const int offv = (row * 128 + hk * 64 + g * 16) ^ ((row & 7) << 4);
          f16x8 vf = *(const f16x8*)((const char*)Vs + offv);
          oa[part][df] = MFMA_F16(pf, vf, oa[part][df]);
        }
      }
      __builtin_amdgcn_s_setprio(0);
    };

    if (dual) {
      // fused dual QK^T: shared K fragments feed both score streams
      f32x4 s0[4], s1[4];
      #pragma unroll
      for (int sf = 0; sf < 4; ++sf) { s0[sf] = z4; s1[sf] = z4; }
      __builtin_amdgcn_s_setprio(1);
      #pragma unroll
      for (int h = 0; h < 2; ++h)
        #pragma unroll
        for (int sf = 0; sf < 4; ++sf) {
          const int row = sf * 16 + lx;
          const int off = (row * 128 + h * 64 + g * 16) ^ ((row & 7) << 4);
          f16x8 kf = *(const f16x8*)((const char*)Ks + off);
          s1[sf] = MFMA_F16(kf, qf[1][h], s1[sf]);
          s0[sf] = MFMA_F16(kf, qf[0][h], s0[sf]);
        }
      __builtin_amdgcn_s_setprio(0);
      sm_store(1, s1, false);          // kt <= qlo < qhi: never diagonal
      sm_store(0, s0, kt == qlo);      // SM0 VALU hides P1-store latency
      pv_acc(1);                       // independent buffers: PVs overlap
      pv_acc(0);
    } else {
      f32x4 s1[4];
      #pragma unroll
      for (int sf = 0; sf < 4; ++sf) s1[sf] = z4;
      __builtin_amdgcn_s_setprio(1);
      #pragma unroll
      for (int h = 0; h < 2; ++h)
        #pragma unroll
        for (int sf = 0; sf < 4; ++sf) {
          const int row = sf * 16 + lx;
          const int off = (row * 128 + h * 64 + g * 16) ^ ((row & 7) << 4);
          f16x8 kf = *(const f16x8*)((const char*)Ks + off);
          s1[sf] = MFMA_F16(kf, qf[1][h], s1[sf]);
        }
      __builtin_amdgcn_s_setprio(0);
      sm_store(1, s1, kt == qhi);
      pv_acc(1);
    }
  }

  // epilogue: write UNNORMALIZED partials (m, l, O) for this split
  const size_t sb = (size_t)split * 64 + bh;
  #pragma unroll
  for (int part = 0; part < 2; ++part) {
    if (lane < 16) {                       // l_i/m_i at lane L are for row0+L
      mPart[sb * SEQ + row0[part] + lane] = m_i[part];
      lPart[sb * SEQ + row0[part] + lane] = l_i[part];
    }
    #pragma unroll
    for (int r = 0; r < 4; ++r) {
      const int t = row0[part] + g * 4 + r;
      f16* dst = Opart + ((size_t)sb * SEQ + t) * HD;
      #pragma unroll
      for (int df = 0; df < 4; ++df)
        dst[df * 16 + lx] = (f16)(oa[part][df][r]);
    }
  }
}

// ---------------------------------------------------------------------------
// Combine the two kv-splits: att[b,t,h*64+d] =
//   (O1*2^(m1-m*) + O2*2^(m2-m*)) / (l1*2^(m1-m*) + l2*2^(m2-m*))
// 8 threads per (bh,t) row, f16x8 per thread.
// ---------------------------------------------------------------------------
__global__ __launch_bounds__(256) void combine_kernel(
    const f16* __restrict__ Opart, const float* __restrict__ mPart,
    const float* __restrict__ lPart, f16* __restrict__ Att) {
  const int G = blockIdx.x * 256 + threadIdx.x;
  const int chunk = G & 7;
  const int rowid = G >> 3;            // bh*SEQ + t, 0..131071
  const int bh = rowid >> 11, t = rowid & (SEQ - 1);
  const int b = bh >> 4, h = bh & 15;
  const size_t i1 = (size_t)bh * SEQ + t;
  const size_t i2 = (size_t)(64 + bh) * SEQ + t;
  const float m1 = mPart[i1], m2 = mPart[i2];
  const float l1 = lPart[i1], l2 = lPart[i2];
  const float mx = fmaxf(m1, m2);
  const float w1 = fast_exp2(m1 - mx), w2 = fast_exp2(m2 - mx);
  const float inv = 1.f / (l1 * w1 + l2 * w2);
  const f16x8 o1 = *(const f16x8*)(Opart + i1 * HD + chunk * 8);
  const f16x8 o2 = *(const f16x8*)(Opart + i2 * HD + chunk * 8);
  f16x8 o;
  #pragma unroll
  for (int j = 0; j < 8; ++j)
    o[j] = (f16)(((float)o1[j] * w1 + (float)o2[j] * w2) * inv);
  *(f16x8*)(Att + ((size_t)b * SEQ + t) * EMB + h * HD + chunk * 8) = o;
}

// ---------------------------------------------------------------------------
// inputs: 0:x 1:mask(ignored) 2:Wq 3:bq 4:Wk 5:bk 6:Wv 7:bv 8:Wo 9:bo
// ws: xh 16MB | w?t 2MB x4 | qh,kh,vth 16MB ea | ath 16MB | Opart 32MB |
//     mPart 1MB | lPart 1MB   = 122MB
// ---------------------------------------------------------------------------
extern "C" void kernel_launch(void* const* d_in, const int* in_sizes, int n_in,
                              void* d_out, int out_size, void* d_ws, size_t ws_size,
                              hipStream_t stream) {
  (void)in_sizes; (void)n_in; (void)out_size; (void)ws_size;
  const float* x  = (const float*)d_in[0];
  const float* Wq = (const float*)d_in[2];
  const float* bq = (const float*)d_in[3];
  const float* Wk = (const float*)d_in[4];
  const float* bk = (const float*)d_in[5];
  const float* Wv = (const float*)d_in[6];
  const float* bv = (const float*)d_in[7];
  const float* Wo = (const float*)d_in[8];
  const float* bo = (const float*)d_in[9];

  f16* xh    = (f16*)d_ws;
  f16* wqt   = xh  + (size_t)MTOT * EMB;
  f16* wkt   = wqt + (size_t)EMB * EMB;
  f16* wvt   = wkt + (size_t)EMB * EMB;
  f16* wot   = wvt + (size_t)EMB * EMB;
  f16* qh    = wot + (size_t)EMB * EMB;
  f16* kh    = qh  + (size_t)MTOT * EMB;
  f16* vth   = kh  + (size_t)MTOT * EMB;
  f16* ath   = vth + (size_t)MTOT * EMB;
  f16* Opart = ath + (size_t)MTOT * EMB;            // [2][64][SEQ][HD]
  float* mP  = (float*)(Opart + (size_t)2 * 64 * SEQ * HD);
  float* lP  = mP + (size_t)2 * 64 * SEQ;

  cast_x_kernel<<<dim3(MTOT * EMB / (256 * 8)), 256, 0, stream>>>(x, xh);
  wtrans_kernel<<<dim3(16, 16, 4), 256, 0, stream>>>(
      Wq, Wk, Wv, Wo, wqt, wkt, wvt, wot);
  qkv_gemm_kernel<<<dim3(MTOT / 128, EMB / 128, 3), 256, 0, stream>>>(
      xh, wqt, wkt, wvt, bq, bk, bv, qh, kh, vth);
  attn_kernel<<<dim3((NT / 2) * 2 * NB * NH), 256, 0, stream>>>(
      qh, kh, vth, Opart, mP, lP);
  combine_kernel<<<dim3(NB * NH * SEQ * 8 / 256), 256, 0, stream>>>(
      Opart, mP, lP, ath);
  proj_gemm_kernel<<<dim3(MTOT / 128, EMB / 128), 256, 0, stream>>>(
      ath, wot, bo, (float*)d_out);
}

// Round 13
// 194.647 us; speedup vs baseline: 1.0309x; 1.0309x over previous
//
#include <hip/hip_runtime.h>

#define SEQ   2048
#define NH    16
#define HD    64
#define EMB   1024
#define NB    4
#define MTOT  (NB*SEQ)   // 8192
#define NT    (SEQ/64)   // 32 kv/q tiles per sequence

typedef _Float16 f16;
typedef _Float16 f16x4 __attribute__((ext_vector_type(4)));
typedef _Float16 f16x8 __attribute__((ext_vector_type(8)));
typedef float    f32x4 __attribute__((ext_vector_type(4)));

#define MFMA_F16(a,b,c) __builtin_amdgcn_mfma_f32_16x16x32_f16(a,b,c,0,0,0)

// Q pre-scale folded into the Q-projection epilogue: 1/sqrt(64) * log2(e)
#define QSCALE 0.18033688011112043f

__device__ __forceinline__ float fast_exp2(float x) {
#if __has_builtin(__builtin_amdgcn_exp2f)
  return __builtin_amdgcn_exp2f(x);
#else
  return exp2f(x);
#endif
}

// global -> LDS direct (16B per lane). LDS dst is wave-uniform base + lane*16.
__device__ __forceinline__ void gload16(const f16* g, f16* l) {
  __builtin_amdgcn_global_load_lds(
      (const __attribute__((address_space(1))) void*)g,
      (__attribute__((address_space(3))) void*)l, 16, 0, 0);
}

// ---------------------------------------------------------------------------
// Prep (merged): z<4 -> Wt[n][k] = (f16)W[k][n] (64x64 tiles through LDS);
//                z>=4 -> cast x (fp32) -> fp16 (512 blocks x 8 chunks).
// ---------------------------------------------------------------------------
__global__ __launch_bounds__(256) void prep_kernel(
    const float* __restrict__ x, f16* __restrict__ xh,
    const float* __restrict__ W0, const float* __restrict__ W1,
    const float* __restrict__ W2, const float* __restrict__ W3,
    f16* __restrict__ O0, f16* __restrict__ O1,
    f16* __restrict__ O2, f16* __restrict__ O3) {
  const int z = blockIdx.z;
  if (z < 4) {
    const float* W = (z==0)?W0:(z==1)?W1:(z==2)?W2:W3;
    f16* O        = (z==0)?O0:(z==1)?O1:(z==2)?O2:O3;
    __shared__ float Tl[64][68];
    const int t = threadIdx.x;
    const int k0 = blockIdx.x * 64, n0 = blockIdx.y * 64;
    {
      const int r = t >> 2, c0 = (t & 3) * 16;
      const float* src = W + (size_t)(k0 + r) * EMB + n0 + c0;
      #pragma unroll
      for (int j = 0; j < 4; ++j) {
        float4 v = *(const float4*)(src + 4 * j);
        Tl[c0+4*j+0][r]=v.x; Tl[c0+4*j+1][r]=v.y;
        Tl[c0+4*j+2][r]=v.z; Tl[c0+4*j+3][r]=v.w;
      }
    }
    __syncthreads();
    {
      const int n = t >> 2, c0 = (t & 3) * 16;
      f16* dst = O + (size_t)(n0 + n) * EMB + k0 + c0;
      #pragma unroll
      for (int j = 0; j < 2; ++j) {
        f16x8 o;
        #pragma unroll
        for (int u = 0; u < 8; ++u) o[u] = (f16)Tl[n][c0 + 8*j + u];
        *(f16x8*)(dst + 8 * j) = o;
      }
    }
  } else {
    const int blk = (z - 4) * 256 + blockIdx.y * 16 + blockIdx.x;  // 0..511
    #pragma unroll
    for (int it = 0; it < 8; ++it) {
      size_t i = (((size_t)blk * 8 + it) * 256 + threadIdx.x) * 8;
      float4 a = *(const float4*)(x + i);
      float4 b = *(const float4*)(x + i + 4);
      f16x8 o;
      o[0]=(f16)a.x; o[1]=(f16)a.y; o[2]=(f16)a.z; o[3]=(f16)a.w;
      o[4]=(f16)b.x; o[5]=(f16)b.y; o[6]=(f16)b.z; o[7]=(f16)b.w;
      *(f16x8*)(xh + i) = o;
    }
  }
}

// ---------------------------------------------------------------------------
// fp16 NT GEMM core: C[m][n] = (sum_k A[m][k] * Bt[n][k] + bias[n]) * scale
// 128x128 tile, BK=64, 4 waves of 64x64, global_load_lds + XOR-swizzled LDS.
// MODE 0: out f16 [B,H,T,D] (q/k)   MODE 1: out f16 [B,H,D,T] (v transposed)
// MODE 2: out f32 row-major [M,N]
// MODE 3: like MODE 2, but A is built on the fly from the two attention
//         kv-split partials: A[m][k] = C1[row]*O1[row][d] + C2[row]*O2[row][d]
//         (row = bh*SEQ+t with bh = b*NH + k0/64), reg-staged + swizzled
//         ds_write to the exact layout gload16 would have produced.
// ---------------------------------------------------------------------------
template<int MODE>
__device__ __forceinline__ void gemm_core(
    const f16* __restrict__ A, const f16* __restrict__ Bt,
    const float* __restrict__ bias, void* __restrict__ out,
    int m0, int n0, float scale,
    const float* __restrict__ C1, const float* __restrict__ C2) {
  __shared__ f16 As[128 * 64];
  __shared__ f16 Bs[128 * 64];
  const int tid  = threadIdx.x;
  const int lane = tid & 63, w = tid >> 6;
  const int g = lane >> 4, lx = lane & 15;
  const int wr = w >> 1, wc = w & 1;
  const int sr = lane >> 3, sc = lane & 7;

  f32x4 acc[4][4];
  const f32x4 z4 = {0.f, 0.f, 0.f, 0.f};
  #pragma unroll
  for (int i = 0; i < 4; ++i)
    #pragma unroll
    for (int j = 0; j < 4; ++j) acc[i][j] = z4;

  for (int k0 = 0; k0 < EMB; k0 += 64) {
    __syncthreads();
    #pragma unroll
    for (int ci = 0; ci < 4; ++ci) {
      const int i = 4 * w + ci;
      const int r = i * 8 + sr;
      const int c = sc ^ (r & 7);
      if (MODE == 3) {
        // combine-staged A: blend the two split partials in-register
        const int m = m0 + r;
        const int b = m >> 11, t = m & (SEQ - 1);
        const size_t row = (size_t)(b * NH + (k0 >> 6)) * SEQ + t;
        const f16x8 o1 = *(const f16x8*)(A + row * HD + c * 8);
        const f16x8 o2 = *(const f16x8*)(A + (size_t)64 * SEQ * HD + row * HD + c * 8);
        const float c1 = C1[row], c2 = C2[row];
        f16x8 a;
        #pragma unroll
        for (int j = 0; j < 8; ++j)
          a[j] = (f16)(c1 * (float)o1[j] + c2 * (float)o2[j]);
        *(f16x8*)((char*)As + i * 1024 + sr * 128 + sc * 16) = a;
      } else {
        gload16(A + (size_t)(m0 + r) * EMB + k0 + c * 8, &As[i * 512]);
      }
      gload16(Bt + (size_t)(n0 + r) * EMB + k0 + c * 8, &Bs[i * 512]);
    }
    __syncthreads();

    #pragma unroll
    for (int h = 0; h < 2; ++h) {
      f16x8 af[4], bf[4];
      #pragma unroll
      for (int mf = 0; mf < 4; ++mf) {
        const int row = wr * 64 + mf * 16 + lx;
        const int off = (row * 128 + h * 64 + g * 16) ^ ((row & 7) << 4);
        af[mf] = *(const f16x8*)((const char*)As + off);
      }
      #pragma unroll
      for (int nf = 0; nf < 4; ++nf) {
        const int row = wc * 64 + nf * 16 + lx;
        const int off = (row * 128 + h * 64 + g * 16) ^ ((row & 7) << 4);
        bf[nf] = *(const f16x8*)((const char*)Bs + off);
      }
      #pragma unroll
      for (int mf = 0; mf < 4; ++mf)
        #pragma unroll
        for (int nf = 0; nf < 4; ++nf)
          acc[mf][nf] = MFMA_F16(af[mf], bf[nf], acc[mf][nf]);
    }
  }

  // epilogue: C/D layout col = lane&15, row = (lane>>4)*4 + reg
  #pragma unroll
  for (int mf = 0; mf < 4; ++mf) {
    #pragma unroll
    for (int nf = 0; nf < 4; ++nf) {
      const int n  = n0 + wc * 64 + nf * 16 + lx;
      const int mb = m0 + wr * 64 + mf * 16 + g * 4;
      const float bv = bias[n];
      if (MODE == 2 || MODE == 3) {
        float* op = (float*)out;
        #pragma unroll
        for (int r = 0; r < 4; ++r)
          op[(size_t)(mb + r) * EMB + n] = acc[mf][nf][r] + bv;
      } else {
        const int b = mb >> 11, tt = mb & (SEQ - 1);
        const int hh = n >> 6, d = n & (HD - 1);
        f16* op = (f16*)out;
        if (MODE == 0) {
          #pragma unroll
          for (int r = 0; r < 4; ++r)
            op[((size_t)(b * NH + hh) * SEQ + tt + r) * HD + d] =
                (f16)((acc[mf][nf][r] + bv) * scale);
        } else {
          f16x4 o;
          #pragma unroll
          for (int r = 0; r < 4; ++r) o[r] = (f16)(acc[mf][nf][r] + bv);
          *(f16x4*)(op + ((size_t)(b * NH + hh) * HD + d) * SEQ + tt) = o;
        }
      }
    }
  }
}

// merged Q/K/V projections: one dispatch, grid.z = 3 -> 1536 blocks in flight
__global__ __launch_bounds__(256) void qkv_gemm_kernel(
    const f16* __restrict__ xh, const f16* __restrict__ wqt,
    const f16* __restrict__ wkt, const f16* __restrict__ wvt,
    const float* __restrict__ bq, const float* __restrict__ bk,
    const float* __restrict__ bv,
    f16* __restrict__ qh, f16* __restrict__ kh, f16* __restrict__ vth) {
  const int z = blockIdx.z;
  const int m0 = blockIdx.x * 128, n0 = blockIdx.y * 128;
  if (z == 0)      gemm_core<0>(xh, wqt, bq, qh, m0, n0, QSCALE, nullptr, nullptr);
  else if (z == 1) gemm_core<0>(xh, wkt, bk, kh, m0, n0, 1.0f, nullptr, nullptr);
  else             gemm_core<1>(xh, wvt, bv, vth, m0, n0, 1.0f, nullptr, nullptr);
}

// proj with fused kv-split combine on the A path
__global__ __launch_bounds__(256) void proj_fused_kernel(
    const f16* __restrict__ Opart, const f16* __restrict__ wot,
    const float* __restrict__ bo, const float* __restrict__ C1,
    const float* __restrict__ C2, float* __restrict__ out) {
  gemm_core<3>(Opart, wot, bo, out, blockIdx.x * 128, blockIdx.y * 128, 1.0f,
               C1, C2);
}

// per-row combine weights: C1 = w1/(l1*w1+l2*w2), C2 = w2/(...)
__global__ __launch_bounds__(256) void lweight_kernel(
    const float* __restrict__ mP, const float* __restrict__ lP,
    float* __restrict__ C1, float* __restrict__ C2) {
  const int i = blockIdx.x * 256 + threadIdx.x;   // 0..131071 = bh*SEQ+t
  const float m1 = mP[i], m2 = mP[i + 64 * SEQ];
  const float l1 = lP[i], l2 = lP[i + 64 * SEQ];
  const float mx = fmaxf(m1, m2);
  const float w1 = fast_exp2(m1 - mx), w2 = fast_exp2(m2 - mx);
  const float inv = 1.f / (l1 * w1 + l2 * w2);
  C1[i] = w1 * inv;
  C2[i] = w2 * inv;
}

// ---------------------------------------------------------------------------
// Causal flash attention — EXACT R11 body (measured best: 84.3 us).
// fp16 MFMA, triangle-paired, XCD-pinned, kv-split=2, shared per-wave P.
// ---------------------------------------------------------------------------
__global__ __launch_bounds__(256, 4) void attn_kernel(
    const f16* __restrict__ Qh, const f16* __restrict__ Kh,
    const f16* __restrict__ Vth, f16* __restrict__ Opart,
    float* __restrict__ mPart, float* __restrict__ lPart) {
  __shared__ f16 Ks[64 * 64];
  __shared__ f16 Vs[64 * 64];
  __shared__ f16 Ps[4][16 * 64];
  const int tid  = threadIdx.x;
  const int lane = tid & 63, w = tid >> 6;
  const int g = lane >> 4, lx = lane & 15;
  const int sr = lane >> 3, sc = lane & 7;
  const int bid = blockIdx.x;
  const int xcd   = bid & 7;
  const int idx   = bid >> 3;          // 0..255
  const int split = idx & 1;           // kv tile parity
  const int p     = (idx >> 1) & 15;   // pair index 0..15
  const int bh    = xcd + 8 * (idx >> 5);
  const int qlo = p, qhi = NT - 1 - p;
  const int nkt = qhi + 1;
  const f16* qp = Qh  + (size_t)bh * SEQ * HD;
  const f16* kp = Kh  + (size_t)bh * SEQ * HD;
  const f16* vp = Vth + (size_t)bh * HD * SEQ;
  const int row0[2] = {qlo * 64 + w * 16, qhi * 64 + w * 16};

  // Q fragments for both parts (B-operand); scale already folded in.
  f16x8 qf[2][2];
  #pragma unroll
  for (int part = 0; part < 2; ++part) {
    const int qrow = row0[part] + lx;
    #pragma unroll
    for (int h = 0; h < 2; ++h)
      qf[part][h] = *(const f16x8*)(qp + (size_t)qrow * HD + h * 32 + g * 8);
  }

  const f32x4 z4 = {0.f, 0.f, 0.f, 0.f};
  f32x4 oa[2][4];
  float m_i[2] = {-1e30f, -1e30f}, l_i[2] = {0.f, 0.f};
  #pragma unroll
  for (int part = 0; part < 2; ++part)
    #pragma unroll
    for (int df = 0; df < 4; ++df) oa[part][df] = z4;

  for (int kt = split; kt < nkt; kt += 2) {
    __syncthreads();   // prior iter's LDS reads done before overwrite
    #pragma unroll
    for (int ci = 0; ci < 2; ++ci) {
      const int i = 2 * w + ci;
      const int r = i * 8 + sr;
      const int c = sc ^ (r & 7);
      gload16(kp + (size_t)(kt * 64 + r) * HD + c * 8, &Ks[i * 512]);
      gload16(vp + (size_t)r * SEQ + kt * 64 + c * 8,  &Vs[i * 512]);
    }
    __syncthreads();

    const int npart = (kt <= qlo) ? 2 : 1;
    #pragma unroll
    for (int pi = 0; pi < 2; ++pi) {
      if (pi >= npart) continue;
      const int part = 1 - pi;               // do part1 first, then part0
      const int qrow = row0[part] + lx;
      const bool diag = (kt == (part ? qhi : qlo));

      // S' = K . Q^T : lane reg r of frag sf: kv = sf*16+g*4+r, q = lx
      f32x4 sa[4];
      #pragma unroll
      for (int sf = 0; sf < 4; ++sf) sa[sf] = z4;
      __builtin_amdgcn_s_setprio(1);
      #pragma unroll
      for (int h = 0; h < 2; ++h)
        #pragma unroll
        for (int sf = 0; sf < 4; ++sf) {
          const int row = sf * 16 + lx;
          const int off = (row * 128 + h * 64 + g * 16) ^ ((row & 7) << 4);
          f16x8 kf = *(const f16x8*)((const char*)Ks + off);
          sa[sf] = MFMA_F16(kf, qf[part][h], sa[sf]);
        }
      __builtin_amdgcn_s_setprio(0);

      // causal mask + online softmax (log2 domain)
      float rmax = -1e30f;
      #pragma unroll
      for (int sf = 0; sf < 4; ++sf)
        #pragma unroll
        for (int r = 0; r < 4; ++r) {
          float vsc = sa[sf][r];
          if (diag) {
            const int kv = kt * 64 + sf * 16 + g * 4 + r;
            if (kv > qrow) vsc = -1e30f;
          }
          sa[sf][r] = vsc;
          rmax = fmaxf(rmax, vsc);
        }
      rmax = fmaxf(rmax, __shfl_xor(rmax, 16));
      rmax = fmaxf(rmax, __shfl_xor(rmax, 32));
      const float mnew = fmaxf(m_i[part], rmax);
      const float corr = fast_exp2(m_i[part] - mnew);
      m_i[part] = mnew;
      float rsum = 0.f;
      #pragma unroll
      for (int sf = 0; sf < 4; ++sf)
        #pragma unroll
        for (int r = 0; r < 4; ++r) {
          const float pv = fast_exp2(sa[sf][r] - mnew);
          sa[sf][r] = pv;
          rsum += pv;
        }
      rsum += __shfl_xor(rsum, 16);
      rsum += __shfl_xor(rsum, 32);
      l_i[part] = l_i[part] * corr + rsum;

      // P -> per-wave LDS transposed to [q=lx][kv] (swizzled)
      #pragma unroll
      for (int sf = 0; sf < 4; ++sf) {
        f16x4 p4;
        #pragma unroll
        for (int r = 0; r < 4; ++r) p4[r] = (f16)sa[sf][r];
        const int off = (lx * 128 + sf * 32 + g * 8) ^ ((lx & 7) << 4);
        *(f16x4*)((char*)Ps[w] + off) = p4;
      }

      // rescale O (row m = g*4+r; its corr lives in lane g*4+r)
      #pragma unroll
      for (int r = 0; r < 4; ++r) {
        const float cr = __shfl(corr, g * 4 + r, 64);
        #pragma unroll
        for (int df = 0; df < 4; ++df) oa[part][df][r] *= cr;
      }

      // O += P @ V
      __builtin_amdgcn_s_setprio(1);
      #pragma unroll
      for (int hk = 0; hk < 2; ++hk) {
        const int offp = (lx * 128 + hk * 64 + g * 16) ^ ((lx & 7) << 4);
        f16x8 pf = *(const f16x8*)((const char*)Ps[w] + offp);
        #pragma unroll
        for (int df = 0; df < 4; ++df) {
          const int row = df * 16 + lx;
          const int offv = (row * 128 + hk * 64 + g * 16) ^ ((row & 7) << 4);
          f16x8 vf = *(const f16x8*)((const char*)Vs + offv);
          oa[part][df] = MFMA_F16(pf, vf, oa[part][df]);
        }
      }
      __builtin_amdgcn_s_setprio(0);
    }
  }

  // epilogue: write UNNORMALIZED partials (m, l, O) for this split
  const size_t sb = (size_t)split * 64 + bh;
  #pragma unroll
  for (int part = 0; part < 2; ++part) {
    if (lane < 16) {                       // l_i/m_i at lane L are for row0+L
      mPart[sb * SEQ + row0[part] + lane] = m_i[part];
      lPart[sb * SEQ + row0[part] + lane] = l_i[part];
    }
    #pragma unroll
    for (int r = 0; r < 4; ++r) {
      const int t = row0[part] + g * 4 + r;
      f16* dst = Opart + ((size_t)sb * SEQ + t) * HD;
      #pragma unroll
      for (int df = 0; df < 4; ++df)
        dst[df * 16 + lx] = (f16)(oa[part][df][r]);
    }
  }
}

// ---------------------------------------------------------------------------
// inputs: 0:x 1:mask(ignored) 2:Wq 3:bq 4:Wk 5:bk 6:Wv 7:bv 8:Wo 9:bo
// ws: xh 16MB | w?t 2MB x4 | qh,kh,vth 16MB ea | Opart 32MB | mP,lP 1MB ea |
//     C1,C2 0.5MB ea   = ~107MB
// ---------------------------------------------------------------------------
extern "C" void kernel_launch(void* const* d_in, const int* in_sizes, int n_in,
                              void* d_out, int out_size, void* d_ws, size_t ws_size,
                              hipStream_t stream) {
  (void)in_sizes; (void)n_in; (void)out_size; (void)ws_size;
  const float* x  = (const float*)d_in[0];
  const float* Wq = (const float*)d_in[2];
  const float* bq = (const float*)d_in[3];
  const float* Wk = (const float*)d_in[4];
  const float* bk = (const float*)d_in[5];
  const float* Wv = (const float*)d_in[6];
  const float* bv = (const float*)d_in[7];
  const float* Wo = (const float*)d_in[8];
  const float* bo = (const float*)d_in[9];

  f16* xh    = (f16*)d_ws;
  f16* wqt   = xh  + (size_t)MTOT * EMB;
  f16* wkt   = wqt + (size_t)EMB * EMB;
  f16* wvt   = wkt + (size_t)EMB * EMB;
  f16* wot   = wvt + (size_t)EMB * EMB;
  f16* qh    = wot + (size_t)EMB * EMB;
  f16* kh    = qh  + (size_t)MTOT * EMB;
  f16* vth   = kh  + (size_t)MTOT * EMB;
  f16* Opart = vth + (size_t)MTOT * EMB;            // [2][64][SEQ][HD]
  float* mP  = (float*)(Opart + (size_t)2 * 64 * SEQ * HD);
  float* lP  = mP + (size_t)2 * 64 * SEQ;
  float* C1  = lP + (size_t)2 * 64 * SEQ;
  float* C2  = C1 + (size_t)64 * SEQ;

  prep_kernel<<<dim3(16, 16, 6), 256, 0, stream>>>(
      x, xh, Wq, Wk, Wv, Wo, wqt, wkt, wvt, wot);
  qkv_gemm_kernel<<<dim3(MTOT / 128, EMB / 128, 3), 256, 0, stream>>>(
      xh, wqt, wkt, wvt, bq, bk, bv, qh, kh, vth);
  attn_kernel<<<dim3((NT / 2) * 2 * NB * NH), 256, 0, stream>>>(
      qh, kh, vth, Opart, mP, lP);
  lweight_kernel<<<dim3(64 * SEQ / 256), 256, 0, stream>>>(mP, lP, C1, C2);
  proj_fused_kernel<<<dim3(MTOT / 128, EMB / 128), 256, 0, stream>>>(
      Opart, wot, bo, C1, C2, (float*)d_out);
}

// Round 15
// 190.727 us; speedup vs baseline: 1.0521x; 1.0206x over previous
//
#include <hip/hip_runtime.h>

#define SEQ   2048
#define NH    16
#define HD    64
#define EMB   1024
#define NB    4
#define MTOT  (NB*SEQ)   // 8192
#define NT    (SEQ/64)   // 32 kv/q tiles per sequence

typedef _Float16 f16;
typedef _Float16 f16x4 __attribute__((ext_vector_type(4)));
typedef _Float16 f16x8 __attribute__((ext_vector_type(8)));
typedef float    f32x4 __attribute__((ext_vector_type(4)));

#define MFMA_F16(a,b,c) __builtin_amdgcn_mfma_f32_16x16x32_f16(a,b,c,0,0,0)

// Q pre-scale folded into the Q-projection epilogue: 1/sqrt(64) * log2(e)
#define QSCALE 0.18033688011112043f

__device__ __forceinline__ float fast_exp2(float x) {
#if __has_builtin(__builtin_amdgcn_exp2f)
  return __builtin_amdgcn_exp2f(x);
#else
  return exp2f(x);
#endif
}

// global -> LDS direct (16B per lane). LDS dst is wave-uniform base + lane*16.
__device__ __forceinline__ void gload16(const f16* g, f16* l) {
  __builtin_amdgcn_global_load_lds(
      (const __attribute__((address_space(1))) void*)g,
      (__attribute__((address_space(3))) void*)l, 16, 0, 0);
}

// ---------------------------------------------------------------------------
// Prep (merged): z<4 -> Wt[n][k] = (f16)W[k][n] (64x64 tiles through LDS);
//                z>=4 -> cast x (fp32) -> fp16 (512 blocks x 8 chunks).
// ---------------------------------------------------------------------------
__global__ __launch_bounds__(256) void prep_kernel(
    const float* __restrict__ x, f16* __restrict__ xh,
    const float* __restrict__ W0, const float* __restrict__ W1,
    const float* __restrict__ W2, const float* __restrict__ W3,
    f16* __restrict__ O0, f16* __restrict__ O1,
    f16* __restrict__ O2, f16* __restrict__ O3) {
  const int z = blockIdx.z;
  if (z < 4) {
    const float* W = (z==0)?W0:(z==1)?W1:(z==2)?W2:W3;
    f16* O        = (z==0)?O0:(z==1)?O1:(z==2)?O2:O3;
    __shared__ float Tl[64][68];
    const int t = threadIdx.x;
    const int k0 = blockIdx.x * 64, n0 = blockIdx.y * 64;
    {
      const int r = t >> 2, c0 = (t & 3) * 16;
      const float* src = W + (size_t)(k0 + r) * EMB + n0 + c0;
      #pragma unroll
      for (int j = 0; j < 4; ++j) {
        float4 v = *(const float4*)(src + 4 * j);
        Tl[c0+4*j+0][r]=v.x; Tl[c0+4*j+1][r]=v.y;
        Tl[c0+4*j+2][r]=v.z; Tl[c0+4*j+3][r]=v.w;
      }
    }
    __syncthreads();
    {
      const int n = t >> 2, c0 = (t & 3) * 16;
      f16* dst = O + (size_t)(n0 + n) * EMB + k0 + c0;
      #pragma unroll
      for (int j = 0; j < 2; ++j) {
        f16x8 o;
        #pragma unroll
        for (int u = 0; u < 8; ++u) o[u] = (f16)Tl[n][c0 + 8*j + u];
        *(f16x8*)(dst + 8 * j) = o;
      }
    }
  } else {
    const int blk = (z - 4) * 256 + blockIdx.y * 16 + blockIdx.x;  // 0..511
    #pragma unroll
    for (int it = 0; it < 8; ++it) {
      size_t i = (((size_t)blk * 8 + it) * 256 + threadIdx.x) * 8;
      float4 a = *(const float4*)(x + i);
      float4 b = *(const float4*)(x + i + 4);
      f16x8 o;
      o[0]=(f16)a.x; o[1]=(f16)a.y; o[2]=(f16)a.z; o[3]=(f16)a.w;
      o[4]=(f16)b.x; o[5]=(f16)b.y; o[6]=(f16)b.z; o[7]=(f16)b.w;
      *(f16x8*)(xh + i) = o;
    }
  }
}

// ---------------------------------------------------------------------------
// fp16 NT GEMM core: C[m][n] = (sum_k A[m][k] * Bt[n][k] + bias[n]) * scale
// 128x128 tile, BK=64, 4 waves of 64x64, global_load_lds + XOR-swizzled LDS.
// MODE 0: out f16 [B,H,T,D] (q/k)   MODE 1: out f16 [B,H,D,T] (v transposed)
// MODE 2: out f32 row-major [M,N]
// ---------------------------------------------------------------------------
template<int MODE>
__device__ __forceinline__ void gemm_core(
    const f16* __restrict__ A, const f16* __restrict__ Bt,
    const float* __restrict__ bias, void* __restrict__ out,
    int m0, int n0, float scale) {
  __shared__ f16 As[128 * 64];
  __shared__ f16 Bs[128 * 64];
  const int tid  = threadIdx.x;
  const int lane = tid & 63, w = tid >> 6;
  const int g = lane >> 4, lx = lane & 15;
  const int wr = w >> 1, wc = w & 1;
  const int sr = lane >> 3, sc = lane & 7;

  f32x4 acc[4][4];
  const f32x4 z4 = {0.f, 0.f, 0.f, 0.f};
  #pragma unroll
  for (int i = 0; i < 4; ++i)
    #pragma unroll
    for (int j = 0; j < 4; ++j) acc[i][j] = z4;

  for (int k0 = 0; k0 < EMB; k0 += 64) {
    __syncthreads();
    #pragma unroll
    for (int ci = 0; ci < 4; ++ci) {
      const int i = 4 * w + ci;
      const int r = i * 8 + sr;
      const int c = sc ^ (r & 7);
      gload16(A  + (size_t)(m0 + r) * EMB + k0 + c * 8, &As[i * 512]);
      gload16(Bt + (size_t)(n0 + r) * EMB + k0 + c * 8, &Bs[i * 512]);
    }
    __syncthreads();

    #pragma unroll
    for (int h = 0; h < 2; ++h) {
      f16x8 af[4], bf[4];
      #pragma unroll
      for (int mf = 0; mf < 4; ++mf) {
        const int row = wr * 64 + mf * 16 + lx;
        const int off = (row * 128 + h * 64 + g * 16) ^ ((row & 7) << 4);
        af[mf] = *(const f16x8*)((const char*)As + off);
      }
      #pragma unroll
      for (int nf = 0; nf < 4; ++nf) {
        const int row = wc * 64 + nf * 16 + lx;
        const int off = (row * 128 + h * 64 + g * 16) ^ ((row & 7) << 4);
        bf[nf] = *(const f16x8*)((const char*)Bs + off);
      }
      #pragma unroll
      for (int mf = 0; mf < 4; ++mf)
        #pragma unroll
        for (int nf = 0; nf < 4; ++nf)
          acc[mf][nf] = MFMA_F16(af[mf], bf[nf], acc[mf][nf]);
    }
  }

  // epilogue: C/D layout col = lane&15, row = (lane>>4)*4 + reg
  #pragma unroll
  for (int mf = 0; mf < 4; ++mf) {
    #pragma unroll
    for (int nf = 0; nf < 4; ++nf) {
      const int n  = n0 + wc * 64 + nf * 16 + lx;
      const int mb = m0 + wr * 64 + mf * 16 + g * 4;
      const float bv = bias[n];
      if (MODE == 2) {
        float* op = (float*)out;
        #pragma unroll
        for (int r = 0; r < 4; ++r)
          op[(size_t)(mb + r) * EMB + n] = acc[mf][nf][r] + bv;
      } else {
        const int b = mb >> 11, tt = mb & (SEQ - 1);
        const int hh = n >> 6, d = n & (HD - 1);
        f16* op = (f16*)out;
        if (MODE == 0) {
          #pragma unroll
          for (int r = 0; r < 4; ++r)
            op[((size_t)(b * NH + hh) * SEQ + tt + r) * HD + d] =
                (f16)((acc[mf][nf][r] + bv) * scale);
        } else {
          f16x4 o;
          #pragma unroll
          for (int r = 0; r < 4; ++r) o[r] = (f16)(acc[mf][nf][r] + bv);
          *(f16x4*)(op + ((size_t)(b * NH + hh) * HD + d) * SEQ + tt) = o;
        }
      }
    }
  }
}

// merged Q/K/V projections: one dispatch, grid.z = 3 -> 1536 blocks in flight
__global__ __launch_bounds__(256) void qkv_gemm_kernel(
    const f16* __restrict__ xh, const f16* __restrict__ wqt,
    const f16* __restrict__ wkt, const f16* __restrict__ wvt,
    const float* __restrict__ bq, const float* __restrict__ bk,
    const float* __restrict__ bv,
    f16* __restrict__ qh, f16* __restrict__ kh, f16* __restrict__ vth) {
  const int z = blockIdx.z;
  const int m0 = blockIdx.x * 128, n0 = blockIdx.y * 128;
  if (z == 0)      gemm_core<0>(xh, wqt, bq, qh, m0, n0, QSCALE);
  else if (z == 1) gemm_core<0>(xh, wkt, bk, kh, m0, n0, 1.0f);
  else             gemm_core<1>(xh, wvt, bv, vth, m0, n0, 1.0f);
}

__global__ __launch_bounds__(256) void proj_gemm_kernel(
    const f16* __restrict__ ath, const f16* __restrict__ wot,
    const float* __restrict__ bo, float* __restrict__ out) {
  gemm_core<2>(ath, wot, bo, out, blockIdx.x * 128, blockIdx.y * 128, 1.0f);
}

// ---------------------------------------------------------------------------
// Causal flash attention — EXACT R11 body (measured best: 84.3 us).
// fp16 MFMA, triangle-paired, XCD-pinned, kv-split=2, shared per-wave P.
// ---------------------------------------------------------------------------
__global__ __launch_bounds__(256, 4) void attn_kernel(
    const f16* __restrict__ Qh, const f16* __restrict__ Kh,
    const f16* __restrict__ Vth, f16* __restrict__ Opart,
    float* __restrict__ mPart, float* __restrict__ lPart) {
  __shared__ f16 Ks[64 * 64];
  __shared__ f16 Vs[64 * 64];
  __shared__ f16 Ps[4][16 * 64];
  const int tid  = threadIdx.x;
  const int lane = tid & 63, w = tid >> 6;
  const int g = lane >> 4, lx = lane & 15;
  const int sr = lane >> 3, sc = lane & 7;
  const int bid = blockIdx.x;
  const int xcd   = bid & 7;
  const int idx   = bid >> 3;          // 0..255
  const int split = idx & 1;           // kv tile parity
  const int p     = (idx >> 1) & 15;   // pair index 0..15
  const int bh    = xcd + 8 * (idx >> 5);
  const int qlo = p, qhi = NT - 1 - p;
  const int nkt = qhi + 1;
  const f16* qp = Qh  + (size_t)bh * SEQ * HD;
  const f16* kp = Kh  + (size_t)bh * SEQ * HD;
  const f16* vp = Vth + (size_t)bh * HD * SEQ;
  const int row0[2] = {qlo * 64 + w * 16, qhi * 64 + w * 16};

  // Q fragments for both parts (B-operand); scale already folded in.
  f16x8 qf[2][2];
  #pragma unroll
  for (int part = 0; part < 2; ++part) {
    const int qrow = row0[part] + lx;
    #pragma unroll
    for (int h = 0; h < 2; ++h)
      qf[part][h] = *(const f16x8*)(qp + (size_t)qrow * HD + h * 32 + g * 8);
  }

  const f32x4 z4 = {0.f, 0.f, 0.f, 0.f};
  f32x4 oa[2][4];
  float m_i[2] = {-1e30f, -1e30f}, l_i[2] = {0.f, 0.f};
  #pragma unroll
  for (int part = 0; part < 2; ++part)
    #pragma unroll
    for (int df = 0; df < 4; ++df) oa[part][df] = z4;

  for (int kt = split; kt < nkt; kt += 2) {
    __syncthreads();   // prior iter's LDS reads done before overwrite
    #pragma unroll
    for (int ci = 0; ci < 2; ++ci) {
      const int i = 2 * w + ci;
      const int r = i * 8 + sr;
      const int c = sc ^ (r & 7);
      gload16(kp + (size_t)(kt * 64 + r) * HD + c * 8, &Ks[i * 512]);
      gload16(vp + (size_t)r * SEQ + kt * 64 + c * 8,  &Vs[i * 512]);
    }
    __syncthreads();

    const int npart = (kt <= qlo) ? 2 : 1;
    #pragma unroll
    for (int pi = 0; pi < 2; ++pi) {
      if (pi >= npart) continue;
      const int part = 1 - pi;               // do part1 first, then part0
      const int qrow = row0[part] + lx;
      const bool diag = (kt == (part ? qhi : qlo));

      // S' = K . Q^T : lane reg r of frag sf: kv = sf*16+g*4+r, q = lx
      f32x4 sa[4];
      #pragma unroll
      for (int sf = 0; sf < 4; ++sf) sa[sf] = z4;
      __builtin_amdgcn_s_setprio(1);
      #pragma unroll
      for (int h = 0; h < 2; ++h)
        #pragma unroll
        for (int sf = 0; sf < 4; ++sf) {
          const int row = sf * 16 + lx;
          const int off = (row * 128 + h * 64 + g * 16) ^ ((row & 7) << 4);
          f16x8 kf = *(const f16x8*)((const char*)Ks + off);
          sa[sf] = MFMA_F16(kf, qf[part][h], sa[sf]);
        }
      __builtin_amdgcn_s_setprio(0);

      // causal mask + online softmax (log2 domain)
      float rmax = -1e30f;
      #pragma unroll
      for (int sf = 0; sf < 4; ++sf)
        #pragma unroll
        for (int r = 0; r < 4; ++r) {
          float vsc = sa[sf][r];
          if (diag) {
            const int kv = kt * 64 + sf * 16 + g * 4 + r;
            if (kv > qrow) vsc = -1e30f;
          }
          sa[sf][r] = vsc;
          rmax = fmaxf(rmax, vsc);
        }
      rmax = fmaxf(rmax, __shfl_xor(rmax, 16));
      rmax = fmaxf(rmax, __shfl_xor(rmax, 32));
      const float mnew = fmaxf(m_i[part], rmax);
      const float corr = fast_exp2(m_i[part] - mnew);
      m_i[part] = mnew;
      float rsum = 0.f;
      #pragma unroll
      for (int sf = 0; sf < 4; ++sf)
        #pragma unroll
        for (int r = 0; r < 4; ++r) {
          const float pv = fast_exp2(sa[sf][r] - mnew);
          sa[sf][r] = pv;
          rsum += pv;
        }
      rsum += __shfl_xor(rsum, 16);
      rsum += __shfl_xor(rsum, 32);
      l_i[part] = l_i[part] * corr + rsum;

      // P -> per-wave LDS transposed to [q=lx][kv] (swizzled)
      #pragma unroll
      for (int sf = 0; sf < 4; ++sf) {
        f16x4 p4;
        #pragma unroll
        for (int r = 0; r < 4; ++r) p4[r] = (f16)sa[sf][r];
        const int off = (lx * 128 + sf * 32 + g * 8) ^ ((lx & 7) << 4);
        *(f16x4*)((char*)Ps[w] + off) = p4;
      }

      // rescale O (row m = g*4+r; its corr lives in lane g*4+r)
      #pragma unroll
      for (int r = 0; r < 4; ++r) {
        const float cr = __shfl(corr, g * 4 + r, 64);
        #pragma unroll
        for (int df = 0; df < 4; ++df) oa[part][df][r] *= cr;
      }

      // O += P @ V
      __builtin_amdgcn_s_setprio(1);
      #pragma unroll
      for (int hk = 0; hk < 2; ++hk) {
        const int offp = (lx * 128 + hk * 64 + g * 16) ^ ((lx & 7) << 4);
        f16x8 pf = *(const f16x8*)((const char*)Ps[w] + offp);
        #pragma unroll
        for (int df = 0; df < 4; ++df) {
          const int row = df * 16 + lx;
          const int offv = (row * 128 + hk * 64 + g * 16) ^ ((row & 7) << 4);
          f16x8 vf = *(const f16x8*)((const char*)Vs + offv);
          oa[part][df] = MFMA_F16(pf, vf, oa[part][df]);
        }
      }
      __builtin_amdgcn_s_setprio(0);
    }
  }

  // epilogue: write UNNORMALIZED partials (m, l, O) for this split
  const size_t sb = (size_t)split * 64 + bh;
  #pragma unroll
  for (int part = 0; part < 2; ++part) {
    if (lane < 16) {                       // l_i/m_i at lane L are for row0+L
      mPart[sb * SEQ + row0[part] + lane] = m_i[part];
      lPart[sb * SEQ + row0[part] + lane] = l_i[part];
    }
    #pragma unroll
    for (int r = 0; r < 4; ++r) {
      const int t = row0[part] + g * 4 + r;
      f16* dst = Opart + ((size_t)sb * SEQ + t) * HD;
      #pragma unroll
      for (int df = 0; df < 4; ++df)
        dst[df * 16 + lx] = (f16)(oa[part][df][r]);
    }
  }
}

// ---------------------------------------------------------------------------
// Combine the two kv-splits: att[b,t,h*64+d] =
//   (O1*2^(m1-m*) + O2*2^(m2-m*)) / (l1*2^(m1-m*) + l2*2^(m2-m*))
// 8 threads per (bh,t) row, f16x8 per thread.
// ---------------------------------------------------------------------------
__global__ __launch_bounds__(256) void combine_kernel(
    const f16* __restrict__ Opart, const float* __restrict__ mPart,
    const float* __restrict__ lPart, f16* __restrict__ Att) {
  const int G = blockIdx.x * 256 + threadIdx.x;
  const int chunk = G & 7;
  const int rowid = G >> 3;            // bh*SEQ + t, 0..131071
  const int bh = rowid >> 11, t = rowid & (SEQ - 1);
  const int b = bh >> 4, h = bh & 15;
  const size_t i1 = (size_t)bh * SEQ + t;
  const size_t i2 = (size_t)(64 + bh) * SEQ + t;
  const float m1 = mPart[i1], m2 = mPart[i2];
  const float l1 = lPart[i1], l2 = lPart[i2];
  const float mx = fmaxf(m1, m2);
  const float w1 = fast_exp2(m1 - mx), w2 = fast_exp2(m2 - mx);
  const float inv = 1.f / (l1 * w1 + l2 * w2);
  const f16x8 o1 = *(const f16x8*)(Opart + i1 * HD + chunk * 8);
  const f16x8 o2 = *(const f16x8*)(Opart + i2 * HD + chunk * 8);
  f16x8 o;
  #pragma unroll
  for (int j = 0; j < 8; ++j)
    o[j] = (f16)(((float)o1[j] * w1 + (float)o2[j] * w2) * inv);
  *(f16x8*)(Att + ((size_t)b * SEQ + t) * EMB + h * HD + chunk * 8) = o;
}

// ---------------------------------------------------------------------------
// inputs: 0:x 1:mask(ignored) 2:Wq 3:bq 4:Wk 5:bk 6:Wv 7:bv 8:Wo 9:bo
// ws: xh 16MB | w?t 2MB x4 | qh,kh,vth 16MB ea | ath 16MB | Opart 32MB |
//     mP,lP 1MB ea   = ~122MB
// ---------------------------------------------------------------------------
extern "C" void kernel_launch(void* const* d_in, const int* in_sizes, int n_in,
                              void* d_out, int out_size, void* d_ws, size_t ws_size,
                              hipStream_t stream) {
  (void)in_sizes; (void)n_in; (void)out_size; (void)ws_size;
  const float* x  = (const float*)d_in[0];
  const float* Wq = (const float*)d_in[2];
  const float* bq = (const float*)d_in[3];
  const float* Wk = (const float*)d_in[4];
  const float* bk = (const float*)d_in[5];
  const float* Wv = (const float*)d_in[6];
  const float* bv = (const float*)d_in[7];
  const float* Wo = (const float*)d_in[8];
  const float* bo = (const float*)d_in[9];

  f16* xh    = (f16*)d_ws;
  f16* wqt   = xh  + (size_t)MTOT * EMB;
  f16* wkt   = wqt + (size_t)EMB * EMB;
  f16* wvt   = wkt + (size_t)EMB * EMB;
  f16* wot   = wvt + (size_t)EMB * EMB;
  f16* qh    = wot + (size_t)EMB * EMB;
  f16* kh    = qh  + (size_t)MTOT * EMB;
  f16* vth   = kh  + (size_t)MTOT * EMB;
  f16* ath   = vth + (size_t)MTOT * EMB;
  f16* Opart = ath + (size_t)MTOT * EMB;            // [2][64][SEQ][HD]
  float* mP  = (float*)(Opart + (size_t)2 * 64 * SEQ * HD);
  float* lP  = mP + (size_t)2 * 64 * SEQ;

  prep_kernel<<<dim3(16, 16, 6), 256, 0, stream>>>(
      x, xh, Wq, Wk, Wv, Wo, wqt, wkt, wvt, wot);
  qkv_gemm_kernel<<<dim3(MTOT / 128, EMB / 128, 3), 256, 0, stream>>>(
      xh, wqt, wkt, wvt, bq, bk, bv, qh, kh, vth);
  attn_kernel<<<dim3((NT / 2) * 2 * NB * NH), 256, 0, stream>>>(
      qh, kh, vth, Opart, mP, lP);
  combine_kernel<<<dim3(NB * NH * SEQ * 8 / 256), 256, 0, stream>>>(
      Opart, mP, lP, ath);
  proj_gemm_kernel<<<dim3(MTOT / 128, EMB / 128), 256, 0, stream>>>(
      ath, wot, bo, (float*)d_out);
}